// Round 13
// baseline (185.287 us; speedup 1.0000x reference)
//
#include <hip/hip_runtime.h>
#include <math.h>

#define NB 8192
#define NI 12288
#define H0 256
#define H1 32
#define H2 32
#define SEGCAP 96          // per-wave quarter-row actives: Poisson(7.5), P(>96)~0
#define OUT_SCALE 300.0f
#define WDL_SCALE 200.0f

typedef float          f32x4 __attribute__((ext_vector_type(4)));
typedef unsigned short u16x4 __attribute__((ext_vector_type(4)));

// ws layout: ftT_bf16 [NI][H0] (6,291,456 B)
#define FTT_B  ((size_t)NI * H0 * 2)
#define WS_NEED FTT_B

#define GAS __attribute__((address_space(1)))
#define LAS __attribute__((address_space(3)))

__device__ __forceinline__ unsigned short f2bf(float f) {
    unsigned u = __float_as_uint(f);
    u += 0x7FFFu + ((u >> 16) & 1u);          // round-to-nearest-even
    return (unsigned short)(u >> 16);
}
__device__ __forceinline__ f32x4 bf4_to_f32(u16x4 h) {
    f32x4 r;
    r.x = __uint_as_float(((unsigned)h.x) << 16);
    r.y = __uint_as_float(((unsigned)h.y) << 16);
    r.z = __uint_as_float(((unsigned)h.z) << 16);
    r.w = __uint_as_float(((unsigned)h.w) << 16);
    return r;
}

// ---------------------------------------------------------------------------
// Kernel 1: tiled transpose + bf16 convert: ft_w [H0][NI] -> ftT [NI][H0] bf16
// ---------------------------------------------------------------------------
__global__ __launch_bounds__(256) void nnue_ft_transpose_bf16(
    const float* __restrict__ src, unsigned short* __restrict__ dst)
{
    __shared__ float tile[64][65];
    const int bx = blockIdx.x, by = blockIdx.y;
    const int tx = threadIdx.x, ty = threadIdx.y;
    const int col = bx * 64 + tx;
    for (int j = ty; j < 64; j += 4)
        tile[j][tx] = src[(size_t)(by * 64 + j) * NI + col];
    __syncthreads();
    const int h = by * 64 + tx;
    for (int j = ty; j < 64; j += 4)
        dst[(size_t)(bx * 64 + j) * H0 + h] = f2bf(tile[tx][j]);
}

// ---------------------------------------------------------------------------
// Kernel 2: fused forward, one 256-thread block per row.
// Stream staged via global_load_lds (async DMA to LDS, vmcnt-counted waits,
// wave-private 2x1KB ring) -> ballot-compact scan from LDS -> wave-private
// segment gather (bf16 table) -> combine -> side-swapped concat -> MLP.
// Stream data never occupies VGPRs; black prologue chunks fly under the
// white gather (R8 overlap preserved).
// ---------------------------------------------------------------------------
__global__ __launch_bounds__(256) void nnue_fwd(
    const float* __restrict__ wf, const float* __restrict__ bf,
    const int* __restrict__ side,
    const unsigned short* __restrict__ ftb16,   // ftT [NI][H0] bf16
    const float* __restrict__ ft_b,
    const float* __restrict__ l1_w, const float* __restrict__ l1_b,
    const float* __restrict__ l2_w, const float* __restrict__ l2_b,
    const float* __restrict__ l3_w, const float* __restrict__ l3_b,
    float* __restrict__ out)
{
    __shared__ float sbuf[4][2][256] __attribute__((aligned(16))); // 8 KB stream ring
    __shared__ int   seg[4][2][SEGCAP];                            // 3 KB
    __shared__ float pacc[4][2][H0] __attribute__((aligned(16)));  // 8 KB
    __shared__ float o0[2 * H0];
    __shared__ float o1[H1];

    const int row = blockIdx.x;
    const int t   = threadIdx.x;
    const int w   = t >> 6;                  // wave id 0..3
    const int l   = t & 63;                  // lane
    const unsigned short* ftl = ftb16 + 4 * l;   // lane owns units 4l..4l+3
    const unsigned long long ltmask = (1ull << l) - 1ull;

    const f32x4* wf4 = (const f32x4*)(wf + (size_t)row * NI);
    const f32x4* bf4 = (const f32x4*)(bf + (size_t)row * NI);

    // issue one wave-wide 1KB chunk: lane data -> sbuf[w][buf][l*4..l*4+3]
    #define GLL(SRC4, c, buf) \
        __builtin_amdgcn_global_load_lds( \
            (const GAS void*)((SRC4) + (c) * 256 + t), \
            (LAS void*)(&sbuf[w][buf][0]), 16, 0, 0);

    #define BALLOT4(vec, kk, lst, n) { \
        const int ebase = (t + (kk) * 256) * 4; \
        { const bool nz = ((vec).x != 0.f); const unsigned long long mk = __ballot(nz); \
          if (mk) { const int pos = __popcll(mk & ltmask); \
                    if (nz && n + pos < SEGCAP) lst[n + pos] = ebase + 0; n += __popcll(mk); } } \
        { const bool nz = ((vec).y != 0.f); const unsigned long long mk = __ballot(nz); \
          if (mk) { const int pos = __popcll(mk & ltmask); \
                    if (nz && n + pos < SEGCAP) lst[n + pos] = ebase + 1; n += __popcll(mk); } } \
        { const bool nz = ((vec).z != 0.f); const unsigned long long mk = __ballot(nz); \
          if (mk) { const int pos = __popcll(mk & ltmask); \
                    if (nz && n + pos < SEGCAP) lst[n + pos] = ebase + 2; n += __popcll(mk); } } \
        { const bool nz = ((vec).w != 0.f); const unsigned long long mk = __ballot(nz); \
          if (mk) { const int pos = __popcll(mk & ltmask); \
                    if (nz && n + pos < SEGCAP) lst[n + pos] = ebase + 3; n += __popcll(mk); } } }

    // one pipeline step: wait chunk c landed (counted vmcnt, never drain the
    // younger in-flight chunk), read own 16B from LDS, lgkm-fence so the read
    // completes before re-issuing into the same ring slot, scan, issue c+2.
    #define STEP(SRC4, c, WL, lst, n) { \
        asm volatile("s_waitcnt vmcnt(" WL ")" ::: "memory"); \
        const f32x4 vv = *(const f32x4*)&sbuf[w][(c) & 1][l * 4]; \
        asm volatile("s_waitcnt lgkmcnt(0)" ::: "memory"); \
        BALLOT4(vv, c, lst, n) \
        if ((c) + 2 < 12) { GLL(SRC4, (c) + 2, ((c) + 2) & 1) } }

    // ---- white scan: LDS-staged, 2-deep ring ----
    int nW = 0;
    {
        int* lst = seg[w][0];
        GLL(wf4, 0, 0)
        GLL(wf4, 1, 1)
        STEP(wf4, 0,  "1", lst, nW) STEP(wf4, 1,  "1", lst, nW)
        STEP(wf4, 2,  "1", lst, nW) STEP(wf4, 3,  "1", lst, nW)
        STEP(wf4, 4,  "1", lst, nW) STEP(wf4, 5,  "1", lst, nW)
        STEP(wf4, 6,  "1", lst, nW) STEP(wf4, 7,  "1", lst, nW)
        STEP(wf4, 8,  "1", lst, nW) STEP(wf4, 9,  "1", lst, nW)
        STEP(wf4, 10, "1", lst, nW) STEP(wf4, 11, "0", lst, nW)
        if (nW > SEGCAP) nW = SEGCAP;
    }

    // ---- black prologue chunks fly under the white gather ----
    GLL(bf4, 0, 0)
    GLL(bf4, 1, 1)

    // ---- gather white: own segment only, 4-way unrolled ----
    {
        f32x4 a0 = {0.f,0.f,0.f,0.f}, a1 = a0, a2 = a0, a3 = a0;
        int i = 0;
        for (; i + 4 <= nW; i += 4) {
            const int i0 = __builtin_amdgcn_readfirstlane(seg[w][0][i]);
            const int i1 = __builtin_amdgcn_readfirstlane(seg[w][0][i + 1]);
            const int i2 = __builtin_amdgcn_readfirstlane(seg[w][0][i + 2]);
            const int i3 = __builtin_amdgcn_readfirstlane(seg[w][0][i + 3]);
            a0 += bf4_to_f32(*(const u16x4*)(ftl + (size_t)i0 * H0));
            a1 += bf4_to_f32(*(const u16x4*)(ftl + (size_t)i1 * H0));
            a2 += bf4_to_f32(*(const u16x4*)(ftl + (size_t)i2 * H0));
            a3 += bf4_to_f32(*(const u16x4*)(ftl + (size_t)i3 * H0));
        }
        for (; i < nW; ++i) {
            const int i0 = __builtin_amdgcn_readfirstlane(seg[w][0][i]);
            a0 += bf4_to_f32(*(const u16x4*)(ftl + (size_t)i0 * H0));
        }
        *(f32x4*)&pacc[w][0][4 * l] = (a0 + a1) + (a2 + a3);
    }

    // ---- black scan: counted waits remain valid upper bounds even though the
    // prologue chunks likely landed during the gather ----
    int nB = 0;
    {
        int* lst = seg[w][1];
        STEP(bf4, 0,  "1", lst, nB) STEP(bf4, 1,  "1", lst, nB)
        STEP(bf4, 2,  "1", lst, nB) STEP(bf4, 3,  "1", lst, nB)
        STEP(bf4, 4,  "1", lst, nB) STEP(bf4, 5,  "1", lst, nB)
        STEP(bf4, 6,  "1", lst, nB) STEP(bf4, 7,  "1", lst, nB)
        STEP(bf4, 8,  "1", lst, nB) STEP(bf4, 9,  "1", lst, nB)
        STEP(bf4, 10, "1", lst, nB) STEP(bf4, 11, "0", lst, nB)
        if (nB > SEGCAP) nB = SEGCAP;
    }
    #undef STEP
    #undef BALLOT4
    #undef GLL

    // ---- gather black ----
    {
        f32x4 b0 = {0.f,0.f,0.f,0.f}, b1 = b0, b2 = b0, b3 = b0;
        int i = 0;
        for (; i + 4 <= nB; i += 4) {
            const int i0 = __builtin_amdgcn_readfirstlane(seg[w][1][i]);
            const int i1 = __builtin_amdgcn_readfirstlane(seg[w][1][i + 1]);
            const int i2 = __builtin_amdgcn_readfirstlane(seg[w][1][i + 2]);
            const int i3 = __builtin_amdgcn_readfirstlane(seg[w][1][i + 3]);
            b0 += bf4_to_f32(*(const u16x4*)(ftl + (size_t)i0 * H0));
            b1 += bf4_to_f32(*(const u16x4*)(ftl + (size_t)i1 * H0));
            b2 += bf4_to_f32(*(const u16x4*)(ftl + (size_t)i2 * H0));
            b3 += bf4_to_f32(*(const u16x4*)(ftl + (size_t)i3 * H0));
        }
        for (; i < nB; ++i) {
            const int i0 = __builtin_amdgcn_readfirstlane(seg[w][1][i]);
            b0 += bf4_to_f32(*(const u16x4*)(ftl + (size_t)i0 * H0));
        }
        *(f32x4*)&pacc[w][1][4 * l] = (b0 + b1) + (b2 + b3);
    }
    __syncthreads();                         // pacc complete (first block sync)

    // ---- combine wave partials; side-swapped concat (thread t owns unit t) ----
    {
        const float ftb  = ft_b[t];
        const float accW = ftb + ((pacc[0][0][t] + pacc[1][0][t]) + (pacc[2][0][t] + pacc[3][0][t]));
        const float accB = ftb + ((pacc[0][1][t] + pacc[1][1][t]) + (pacc[2][1][t] + pacc[3][1][t]));
        const bool s = side[row] != 0;
        const float wv = fminf(fmaxf(accW, 0.f), 1.f);
        const float bv = fminf(fmaxf(accB, 0.f), 1.f);
        o0[t]      = s ? wv : bv;
        o0[t + H0] = s ? bv : wv;
    }
    __syncthreads();

    // ---- l1: 32 outputs x 512 inputs, 8 threads per output ----
    {
        const int j = t >> 3, p = t & 7;
        const float* wrow = l1_w + j * (2 * H0);
        float sum = 0.f;
        #pragma unroll
        for (int m2 = 0; m2 < 64; ++m2) {
            const int k = p + 8 * m2;        // stride-8: conflict-free LDS
            sum += wrow[k] * o0[k];
        }
        sum += __shfl_xor(sum, 1);
        sum += __shfl_xor(sum, 2);
        sum += __shfl_xor(sum, 4);
        if (p == 0) o1[j] = fminf(fmaxf(sum + l1_b[j], 0.f), 1.f);
    }
    __syncthreads();

    // ---- l2 (32x32) + l3 (1x32) + sigmoid ----
    if (t < 32) {
        const float* wrow = l2_w + t * H1;
        float sum2 = 0.f;
        #pragma unroll
        for (int k = 0; k < H1; ++k) sum2 += wrow[k] * o1[k];
        const float o2v = fminf(fmaxf(sum2 + l2_b[t], 0.f), 1.f);
        float part = o2v * l3_w[t];
        part += __shfl_xor(part, 1);
        part += __shfl_xor(part, 2);
        part += __shfl_xor(part, 4);
        part += __shfl_xor(part, 8);
        part += __shfl_xor(part, 16);
        if (t == 0) {
            const float o3 = (part + l3_b[0]) * OUT_SCALE;
            out[row] = 1.f / (1.f + __expf(-o3 / WDL_SCALE));
        }
    }
}

// ---------------------------------------------------------------------------
// Fallback (ws too small): fused kernel, untransposed strided fp32 gather.
// ---------------------------------------------------------------------------
__global__ __launch_bounds__(256) void nnue_fused_fallback(
    const float* __restrict__ wf, const float* __restrict__ bf,
    const int* __restrict__ side,
    const float* __restrict__ ft,        // ft_w [H0][NI]
    const float* __restrict__ ft_b,
    const float* __restrict__ l1_w, const float* __restrict__ l1_b,
    const float* __restrict__ l2_w, const float* __restrict__ l2_b,
    const float* __restrict__ l3_w, const float* __restrict__ l3_b,
    float* __restrict__ out)
{
    __shared__ int   idxW[256], idxB[256];
    __shared__ int   cnts[2];
    __shared__ float o0[2 * H0];
    __shared__ float o1[H1];

    const int row = blockIdx.x;
    const int t   = threadIdx.x;
    if (t < 2) cnts[t] = 0;
    __syncthreads();

    const f32x4* wf4 = (const f32x4*)(wf + (size_t)row * NI);
    const f32x4* bf4 = (const f32x4*)(bf + (size_t)row * NI);
    const float ftb = ft_b[t];

    for (int half = 0; half < 2; ++half) {
        const f32x4* p4 = half ? bf4 : wf4;
        int* lst = half ? idxB : idxW;
        f32x4 v[12];
        #pragma unroll
        for (int k = 0; k < 12; ++k)
            v[k] = __builtin_nontemporal_load(&p4[t + k * 256]);
        #pragma unroll
        for (int k = 0; k < 12; ++k) {
            const int base = (t + k * 256) * 4;
            int m = (v[k].x != 0.f ? 1 : 0) | (v[k].y != 0.f ? 2 : 0)
                  | (v[k].z != 0.f ? 4 : 0) | (v[k].w != 0.f ? 8 : 0);
            while (m) {
                const int b = __ffs(m) - 1;
                m &= m - 1;
                lst[atomicAdd(&cnts[half], 1)] = base + b;
            }
        }
    }
    __syncthreads();

    const int nW = cnts[0], nB = cnts[1];
    float accW = ftb, accB = ftb;
    const float* ftr = ft + (size_t)t * NI;
    for (int j = 0; j < nW; ++j) accW += ftr[idxW[j]];
    for (int j = 0; j < nB; ++j) accB += ftr[idxB[j]];

    const bool s = side[row] != 0;
    const float wv = fminf(fmaxf(accW, 0.f), 1.f);
    const float bv = fminf(fmaxf(accB, 0.f), 1.f);
    o0[t]      = s ? wv : bv;
    o0[t + H0] = s ? bv : wv;
    __syncthreads();

    {
        const int j = t >> 3, p = t & 7;
        const float* wrow = l1_w + j * (2 * H0);
        float sum = 0.f;
        #pragma unroll
        for (int m = 0; m < 64; ++m) sum += wrow[p + 8 * m] * o0[p + 8 * m];
        sum += __shfl_xor(sum, 1);
        sum += __shfl_xor(sum, 2);
        sum += __shfl_xor(sum, 4);
        if (p == 0) o1[j] = fminf(fmaxf(sum + l1_b[j], 0.f), 1.f);
    }
    __syncthreads();

    if (t < 32) {
        const float* wrow = l2_w + t * H1;
        float sum2 = 0.f;
        #pragma unroll
        for (int k = 0; k < H1; ++k) sum2 += wrow[k] * o1[k];
        const float o2v = fminf(fmaxf(sum2 + l2_b[t], 0.f), 1.f);
        float part = o2v * l3_w[t];
        part += __shfl_xor(part, 1);
        part += __shfl_xor(part, 2);
        part += __shfl_xor(part, 4);
        part += __shfl_xor(part, 8);
        part += __shfl_xor(part, 16);
        if (t == 0) {
            const float o3 = (part + l3_b[0]) * OUT_SCALE;
            out[row] = 1.f / (1.f + __expf(-o3 / WDL_SCALE));
        }
    }
}

extern "C" void kernel_launch(void* const* d_in, const int* in_sizes, int n_in,
                              void* d_out, int out_size, void* d_ws, size_t ws_size,
                              hipStream_t stream) {
    const float* wf   = (const float*)d_in[0];
    const float* bf   = (const float*)d_in[1];
    const int*   side = (const int*)d_in[2];
    const float* ft_w = (const float*)d_in[3];
    const float* ft_b = (const float*)d_in[4];
    const float* l1_w = (const float*)d_in[5];
    const float* l1_b = (const float*)d_in[6];
    const float* l2_w = (const float*)d_in[7];
    const float* l2_b = (const float*)d_in[8];
    const float* l3_w = (const float*)d_in[9];
    const float* l3_b = (const float*)d_in[10];
    float*       out  = (float*)d_out;

    if (ws_size >= WS_NEED) {
        unsigned short* ftT = (unsigned short*)d_ws;
        nnue_ft_transpose_bf16<<<dim3(NI / 64, H0 / 64), dim3(64, 4), 0, stream>>>(ft_w, ftT);
        nnue_fwd<<<NB, 256, 0, stream>>>(wf, bf, side, ftT, ft_b,
                                         l1_w, l1_b, l2_w, l2_b, l3_w, l3_b, out);
    } else {
        nnue_fused_fallback<<<NB, 256, 0, stream>>>(wf, bf, side, ft_w, ft_b,
                                                    l1_w, l1_b, l2_w, l2_b,
                                                    l3_w, l3_b, out);
    }
}

// Round 14
// 152.948 us; speedup vs baseline: 1.2114x; 1.2114x over previous
//
#include <hip/hip_runtime.h>
#include <math.h>

#define NB 8192
#define NI 12288
#define H0 256
#define H1 32
#define H2 32
#define SEGCAP 96          // per-wave half-row actives: Poisson(15), P(>96)~0
#define OUT_SCALE 300.0f
#define WDL_SCALE 200.0f

typedef float          f32x4 __attribute__((ext_vector_type(4)));
typedef unsigned short u16x4 __attribute__((ext_vector_type(4)));

// ws layout: ftT_bf16 [NI][H0] (6,291,456 B)
#define FTT_B  ((size_t)NI * H0 * 2)
#define WS_NEED FTT_B

__device__ __forceinline__ unsigned short f2bf(float f) {
    unsigned u = __float_as_uint(f);
    u += 0x7FFFu + ((u >> 16) & 1u);          // round-to-nearest-even
    return (unsigned short)(u >> 16);
}
__device__ __forceinline__ f32x4 bf4_to_f32(u16x4 h) {
    f32x4 r;
    r.x = __uint_as_float(((unsigned)h.x) << 16);
    r.y = __uint_as_float(((unsigned)h.y) << 16);
    r.z = __uint_as_float(((unsigned)h.z) << 16);
    r.w = __uint_as_float(((unsigned)h.w) << 16);
    return r;
}

// ---------------------------------------------------------------------------
// Kernel 1: tiled transpose + bf16 convert: ft_w [H0][NI] -> ftT [NI][H0] bf16
// ---------------------------------------------------------------------------
__global__ __launch_bounds__(256) void nnue_ft_transpose_bf16(
    const float* __restrict__ src, unsigned short* __restrict__ dst)
{
    __shared__ float tile[64][65];
    const int bx = blockIdx.x, by = blockIdx.y;
    const int tx = threadIdx.x, ty = threadIdx.y;
    const int col = bx * 64 + tx;
    for (int j = ty; j < 64; j += 4)
        tile[j][tx] = src[(size_t)(by * 64 + j) * NI + col];
    __syncthreads();
    const int h = by * 64 + tx;
    for (int j = ty; j < 64; j += 4)
        dst[(size_t)(bx * 64 + j) * H0 + h] = f2bf(tile[tx][j]);
}

// ---------------------------------------------------------------------------
// Kernel 2: fused forward, one 256-thread block per row.
// PERSPECTIVE-PARALLEL WAVES: waves 0-1 scan+gather white (half-row each),
// waves 2-3 black. Each wave's vmcnt queue holds ONLY its own loads, so its
// gather is never blocked by the other perspective's stream (in-order vmcnt
// retirement). Streams of the other waves fly during this wave's gather.
// Ballot compaction (no atomics), wave-private segments, one sync at combine.
// ---------------------------------------------------------------------------
__global__ __launch_bounds__(256) void nnue_fwd(
    const float* __restrict__ wf, const float* __restrict__ bf,
    const int* __restrict__ side,
    const unsigned short* __restrict__ ftb16,   // ftT [NI][H0] bf16
    const float* __restrict__ ft_b,
    const float* __restrict__ l1_w, const float* __restrict__ l1_b,
    const float* __restrict__ l2_w, const float* __restrict__ l2_b,
    const float* __restrict__ l3_w, const float* __restrict__ l3_b,
    float* __restrict__ out)
{
    __shared__ int   seg[4][SEGCAP];                               // per-wave lists
    __shared__ float pacc[4][H0] __attribute__((aligned(16)));     // per-wave partials
    __shared__ float o0[2 * H0];
    __shared__ float o1[H1];

    const int row = blockIdx.x;
    const int t   = threadIdx.x;
    const int w   = t >> 6;                  // wave id 0..3
    const int l   = t & 63;                  // lane
    const int hf  = w & 1;                   // half-row 0/1
    const unsigned short* ftl = ftb16 + 4 * l;   // lane owns units 4l..4l+3
    const unsigned long long ltmask = (1ull << l) - 1ull;

    // wave 0,1 -> white; wave 2,3 -> black. Each covers f32x4 [hf*1536, hf*1536+1536)
    const float* srcp = (w < 2) ? wf : bf;
    const f32x4* s4 = (const f32x4*)(srcp + (size_t)row * NI) + hf * 1536;

    #define BALLOT4(vec, kk, lst, n) { \
        const int ebase = (hf * 1536 + (kk) * 64 + l) * 4; \
        { const bool nz = ((vec).x != 0.f); const unsigned long long mk = __ballot(nz); \
          if (mk) { const int pos = __popcll(mk & ltmask); \
                    if (nz && n + pos < SEGCAP) lst[n + pos] = ebase + 0; n += __popcll(mk); } } \
        { const bool nz = ((vec).y != 0.f); const unsigned long long mk = __ballot(nz); \
          if (mk) { const int pos = __popcll(mk & ltmask); \
                    if (nz && n + pos < SEGCAP) lst[n + pos] = ebase + 1; n += __popcll(mk); } } \
        { const bool nz = ((vec).z != 0.f); const unsigned long long mk = __ballot(nz); \
          if (mk) { const int pos = __popcll(mk & ltmask); \
                    if (nz && n + pos < SEGCAP) lst[n + pos] = ebase + 2; n += __popcll(mk); } } \
        { const bool nz = ((vec).w != 0.f); const unsigned long long mk = __ballot(nz); \
          if (mk) { const int pos = __popcll(mk & ltmask); \
                    if (nz && n + pos < SEGCAP) lst[n + pos] = ebase + 3; n += __popcll(mk); } } }

    // ---- scan 24 f32x4/lane, 12-deep pipeline (load12 / proc6+load6 x2 / drain)
    int n = 0;
    {
        int* lst = seg[w];
        f32x4 v[12];
        #pragma unroll
        for (int k = 0; k < 12; ++k)
            v[k] = __builtin_nontemporal_load(&s4[k * 64 + l]);
        #pragma unroll
        for (int k = 0; k < 6; ++k) BALLOT4(v[k], k, lst, n)        // frees v[0..5]
        #pragma unroll
        for (int k = 0; k < 6; ++k)
            v[k] = __builtin_nontemporal_load(&s4[(12 + k) * 64 + l]);
        #pragma unroll
        for (int k = 6; k < 12; ++k) BALLOT4(v[k], k, lst, n)       // frees v[6..11]
        #pragma unroll
        for (int k = 0; k < 6; ++k)
            v[k + 6] = __builtin_nontemporal_load(&s4[(18 + k) * 64 + l]);
        #pragma unroll
        for (int k = 0; k < 6; ++k) BALLOT4(v[k], 12 + k, lst, n)
        #pragma unroll
        for (int k = 6; k < 12; ++k) BALLOT4(v[k], 12 + k, lst, n)
        if (n > SEGCAP) n = SEGCAP;
    }
    #undef BALLOT4

    // ---- gather own segment: only own loads in this wave's vmcnt queue ----
    {
        f32x4 a0 = {0.f,0.f,0.f,0.f}, a1 = a0, a2 = a0, a3 = a0;
        int i = 0;
        for (; i + 4 <= n; i += 4) {
            const int i0 = __builtin_amdgcn_readfirstlane(seg[w][i]);
            const int i1 = __builtin_amdgcn_readfirstlane(seg[w][i + 1]);
            const int i2 = __builtin_amdgcn_readfirstlane(seg[w][i + 2]);
            const int i3 = __builtin_amdgcn_readfirstlane(seg[w][i + 3]);
            a0 += bf4_to_f32(*(const u16x4*)(ftl + (size_t)i0 * H0));
            a1 += bf4_to_f32(*(const u16x4*)(ftl + (size_t)i1 * H0));
            a2 += bf4_to_f32(*(const u16x4*)(ftl + (size_t)i2 * H0));
            a3 += bf4_to_f32(*(const u16x4*)(ftl + (size_t)i3 * H0));
        }
        for (; i < n; ++i) {
            const int i0 = __builtin_amdgcn_readfirstlane(seg[w][i]);
            a0 += bf4_to_f32(*(const u16x4*)(ftl + (size_t)i0 * H0));
        }
        *(f32x4*)&pacc[w][4 * l] = (a0 + a1) + (a2 + a3);
    }
    __syncthreads();                         // all four partials complete

    // ---- combine halves; side-swapped concat (thread t owns unit t) ----
    {
        const float ftb  = ft_b[t];
        const float accW = ftb + pacc[0][t] + pacc[1][t];
        const float accB = ftb + pacc[2][t] + pacc[3][t];
        const bool s = side[row] != 0;
        const float wv = fminf(fmaxf(accW, 0.f), 1.f);
        const float bv = fminf(fmaxf(accB, 0.f), 1.f);
        o0[t]      = s ? wv : bv;
        o0[t + H0] = s ? bv : wv;
    }
    __syncthreads();

    // ---- l1: 32 outputs x 512 inputs, 8 threads per output ----
    {
        const int j = t >> 3, p = t & 7;
        const float* wrow = l1_w + j * (2 * H0);
        float sum = 0.f;
        #pragma unroll
        for (int m2 = 0; m2 < 64; ++m2) {
            const int k = p + 8 * m2;        // stride-8: conflict-free LDS
            sum += wrow[k] * o0[k];
        }
        sum += __shfl_xor(sum, 1);
        sum += __shfl_xor(sum, 2);
        sum += __shfl_xor(sum, 4);
        if (p == 0) o1[j] = fminf(fmaxf(sum + l1_b[j], 0.f), 1.f);
    }
    __syncthreads();

    // ---- l2 (32x32) + l3 (1x32) + sigmoid ----
    if (t < 32) {
        const float* wrow = l2_w + t * H1;
        float sum2 = 0.f;
        #pragma unroll
        for (int k = 0; k < H1; ++k) sum2 += wrow[k] * o1[k];
        const float o2v = fminf(fmaxf(sum2 + l2_b[t], 0.f), 1.f);
        float part = o2v * l3_w[t];
        part += __shfl_xor(part, 1);
        part += __shfl_xor(part, 2);
        part += __shfl_xor(part, 4);
        part += __shfl_xor(part, 8);
        part += __shfl_xor(part, 16);
        if (t == 0) {
            const float o3 = (part + l3_b[0]) * OUT_SCALE;
            out[row] = 1.f / (1.f + __expf(-o3 / WDL_SCALE));
        }
    }
}

// ---------------------------------------------------------------------------
// Fallback (ws too small): fused kernel, untransposed strided fp32 gather.
// ---------------------------------------------------------------------------
__global__ __launch_bounds__(256) void nnue_fused_fallback(
    const float* __restrict__ wf, const float* __restrict__ bf,
    const int* __restrict__ side,
    const float* __restrict__ ft,        // ft_w [H0][NI]
    const float* __restrict__ ft_b,
    const float* __restrict__ l1_w, const float* __restrict__ l1_b,
    const float* __restrict__ l2_w, const float* __restrict__ l2_b,
    const float* __restrict__ l3_w, const float* __restrict__ l3_b,
    float* __restrict__ out)
{
    __shared__ int   idxW[256], idxB[256];
    __shared__ int   cnts[2];
    __shared__ float o0[2 * H0];
    __shared__ float o1[H1];

    const int row = blockIdx.x;
    const int t   = threadIdx.x;
    if (t < 2) cnts[t] = 0;
    __syncthreads();

    const f32x4* wf4 = (const f32x4*)(wf + (size_t)row * NI);
    const f32x4* bf4 = (const f32x4*)(bf + (size_t)row * NI);
    const float ftb = ft_b[t];

    for (int half = 0; half < 2; ++half) {
        const f32x4* p4 = half ? bf4 : wf4;
        int* lst = half ? idxB : idxW;
        f32x4 v[12];
        #pragma unroll
        for (int k = 0; k < 12; ++k)
            v[k] = __builtin_nontemporal_load(&p4[t + k * 256]);
        #pragma unroll
        for (int k = 0; k < 12; ++k) {
            const int base = (t + k * 256) * 4;
            int m = (v[k].x != 0.f ? 1 : 0) | (v[k].y != 0.f ? 2 : 0)
                  | (v[k].z != 0.f ? 4 : 0) | (v[k].w != 0.f ? 8 : 0);
            while (m) {
                const int b = __ffs(m) - 1;
                m &= m - 1;
                lst[atomicAdd(&cnts[half], 1)] = base + b;
            }
        }
    }
    __syncthreads();

    const int nW = cnts[0], nB = cnts[1];
    float accW = ftb, accB = ftb;
    const float* ftr = ft + (size_t)t * NI;
    for (int j = 0; j < nW; ++j) accW += ftr[idxW[j]];
    for (int j = 0; j < nB; ++j) accB += ftr[idxB[j]];

    const bool s = side[row] != 0;
    const float wv = fminf(fmaxf(accW, 0.f), 1.f);
    const float bv = fminf(fmaxf(accB, 0.f), 1.f);
    o0[t]      = s ? wv : bv;
    o0[t + H0] = s ? bv : wv;
    __syncthreads();

    {
        const int j = t >> 3, p = t & 7;
        const float* wrow = l1_w + j * (2 * H0);
        float sum = 0.f;
        #pragma unroll
        for (int m = 0; m < 64; ++m) sum += wrow[p + 8 * m] * o0[p + 8 * m];
        sum += __shfl_xor(sum, 1);
        sum += __shfl_xor(sum, 2);
        sum += __shfl_xor(sum, 4);
        if (p == 0) o1[j] = fminf(fmaxf(sum + l1_b[j], 0.f), 1.f);
    }
    __syncthreads();

    if (t < 32) {
        const float* wrow = l2_w + t * H1;
        float sum2 = 0.f;
        #pragma unroll
        for (int k = 0; k < H1; ++k) sum2 += wrow[k] * o1[k];
        const float o2v = fminf(fmaxf(sum2 + l2_b[t], 0.f), 1.f);
        float part = o2v * l3_w[t];
        part += __shfl_xor(part, 1);
        part += __shfl_xor(part, 2);
        part += __shfl_xor(part, 4);
        part += __shfl_xor(part, 8);
        part += __shfl_xor(part, 16);
        if (t == 0) {
            const float o3 = (part + l3_b[0]) * OUT_SCALE;
            out[row] = 1.f / (1.f + __expf(-o3 / WDL_SCALE));
        }
    }
}

extern "C" void kernel_launch(void* const* d_in, const int* in_sizes, int n_in,
                              void* d_out, int out_size, void* d_ws, size_t ws_size,
                              hipStream_t stream) {
    const float* wf   = (const float*)d_in[0];
    const float* bf   = (const float*)d_in[1];
    const int*   side = (const int*)d_in[2];
    const float* ft_w = (const float*)d_in[3];
    const float* ft_b = (const float*)d_in[4];
    const float* l1_w = (const float*)d_in[5];
    const float* l1_b = (const float*)d_in[6];
    const float* l2_w = (const float*)d_in[7];
    const float* l2_b = (const float*)d_in[8];
    const float* l3_w = (const float*)d_in[9];
    const float* l3_b = (const float*)d_in[10];
    float*       out  = (float*)d_out;

    if (ws_size >= WS_NEED) {
        unsigned short* ftT = (unsigned short*)d_ws;
        nnue_ft_transpose_bf16<<<dim3(NI / 64, H0 / 64), dim3(64, 4), 0, stream>>>(ft_w, ftT);
        nnue_fwd<<<NB, 256, 0, stream>>>(wf, bf, side, ftT, ft_b,
                                         l1_w, l1_b, l2_w, l2_b, l3_w, l3_b, out);
    } else {
        nnue_fused_fallback<<<NB, 256, 0, stream>>>(wf, bf, side, ft_w, ft_b,
                                                    l1_w, l1_b, l2_w, l2_b,
                                                    l3_w, l3_b, out);
    }
}